// Round 13
// baseline (1138.323 us; speedup 1.0000x reference)
//
#include <hip/hip_runtime.h>

static constexpr int NN  = 100000;   // nodes
static constexpr int NE  = 1200000;  // edges
static constexpr int KIN = 256;      // input dim
static constexpr int HID = 64;       // hidden == output dim

static constexpr int BSH   = 7;                      // log2 nodes-per-bucket
static constexpr int NPB   = 1 << BSH;               // 128 nodes per bucket
static constexpr int NB    = (NN + NPB - 1) / NPB;   // 782 buckets
static constexpr int CHUNK = 8192;                   // edges per binning block
static constexpr int NBK   = (NE + CHUNK - 1) / CHUNK; // 147 binning blocks

typedef __attribute__((ext_vector_type(8))) __bf16 bf16v8;
typedef __attribute__((ext_vector_type(4))) float f32x4;

// ---------- bf16 helpers (exact widen; RNE narrow)
__device__ __forceinline__ float bf2f(unsigned short u) {
  return __uint_as_float(((unsigned int)u) << 16);
}
__device__ __forceinline__ unsigned short f2bf(float f) {
  unsigned int b = __float_as_uint(f);
  return (unsigned short)((b + 0x7FFFu + ((b >> 16) & 1u)) >> 16);
}

// ---------- W fp32 -> bf16 hi/lo tables (hi = RNE(bf16), lo = RNE(x - hi))
__global__ void k_wconv(const float* __restrict__ Wsrc, __bf16* __restrict__ Whi,
                        __bf16* __restrict__ Wlo, int n) {
  int i = blockIdx.x * 256 + threadIdx.x;
  if (i < n) {
    float v = Wsrc[i];
    __bf16 h = (__bf16)v;
    Whi[i] = h;
    Wlo[i] = (__bf16)(v - (float)h);
  }
}

// ---------- pass 1: per-(block,bucket) histogram of dst buckets
__global__ void __launch_bounds__(256) k_bhist(const int* __restrict__ ed, int* __restrict__ bcnt) {
  __shared__ int lcnt[NB];
  int t = threadIdx.x, blk = blockIdx.x;
  for (int i = t; i < NB; i += 256) lcnt[i] = 0;
  __syncthreads();
  int base = blk * CHUNK;
  #pragma unroll
  for (int it = 0; it < CHUNK / 256; ++it) {
    int e = base + it * 256 + t;
    if (e < NE) atomicAdd(&lcnt[ed[NE + e] >> BSH], 1);
  }
  __syncthreads();
  for (int i = t; i < NB; i += 256) bcnt[blk * NB + i] = lcnt[i];
}

// ---------- scan A: per bucket, exclusive prefix over blocks (in place) + totals
__global__ void k_bscan1(int* __restrict__ bcnt, int* __restrict__ tot) {
  int b = blockIdx.x * 256 + threadIdx.x;
  if (b >= NB) return;
  int run = 0;
  for (int k = 0; k < NBK; ++k) {
    int v = bcnt[k * NB + b];
    bcnt[k * NB + b] = run;
    run += v;
  }
  tot[b] = run;
}

// ---------- scan B: exclusive prefix over bucket totals
__global__ void k_bscan2(const int* __restrict__ tot, int* __restrict__ basep) {
  __shared__ int sh[1024];
  int t = threadIdx.x;
  int v = (t < NB) ? tot[t] : 0;
  sh[t] = v;
  __syncthreads();
  #pragma unroll
  for (int off = 1; off < 1024; off <<= 1) {
    int x = (t >= off) ? sh[t - off] : 0;
    __syncthreads();
    sh[t] += x;
    __syncthreads();
  }
  if (t < NB) basep[t] = sh[t] - v;  // exclusive
}

// ---------- pass 2: scatter edges into bucket-grouped array (contiguous per block/bucket)
__global__ void __launch_bounds__(256) k_bin(const int* __restrict__ ed, const int* __restrict__ bcnt,
                                             const int* __restrict__ basep, unsigned* __restrict__ binned) {
  __shared__ int lcnt[NB];
  int t = threadIdx.x, blk = blockIdx.x;
  for (int i = t; i < NB; i += 256) lcnt[i] = 0;
  __syncthreads();
  int base = blk * CHUNK;
  #pragma unroll
  for (int it = 0; it < CHUNK / 256; ++it) {
    int e = base + it * 256 + t;
    if (e < NE) {
      int src = ed[e];
      int dst = ed[NE + e];
      int b = dst >> BSH;
      int r = atomicAdd(&lcnt[b], 1);
      int pos = basep[b] + bcnt[blk * NB + b] + r;
      binned[pos] = (unsigned)src | ((unsigned)(dst & (NPB - 1)) << 17);
    }
  }
}

// ---------- per-bucket degree count (LDS-local, no global random atomics)
__global__ void __launch_bounds__(256) k_degb(const unsigned* __restrict__ binned,
                                              const int* __restrict__ basep, const int* __restrict__ tot,
                                              int* __restrict__ deg) {
  __shared__ int d[NPB];
  int t = threadIdx.x, b = blockIdx.x;
  if (t < NPB) d[t] = 0;
  __syncthreads();
  int s = basep[b], n = tot[b];
  for (int i = t; i < n; i += 256) atomicAdd(&d[binned[s + i] >> 17], 1);
  __syncthreads();
  int node = b * NPB + t;
  if (t < NPB && node < NN) deg[node] = d[t];
}

__global__ void k_dinv(const int* __restrict__ deg, float* __restrict__ dinv) {
  int i = blockIdx.x * 256 + threadIdx.x;
  if (i < NN) dinv[i] = rsqrtf((float)(deg[i] + 1));
}

// ---------- MFMA GEMM (unchanged from round 12): Y = X @ W^T via bf16 hi/lo 3-term split
template<int K, int MODE>
__global__ void __launch_bounds__(256, 4)
k_gemm(const float* __restrict__ X, const __bf16* __restrict__ Whi, const __bf16* __restrict__ Wlo,
       const float* __restrict__ dinv, const float* __restrict__ bias, void* __restrict__ Yv) {
  constexpr int KT = 32;
  constexpr int NT = K / KT;
  constexpr int LS = 40;
  constexpr int CS = 68;
  __shared__ __align__(16) char smem[4 * 64 * LS * 2];
  __bf16* xh = (__bf16*)smem;
  __bf16* xl = xh + 64 * LS;
  __bf16* wh = xl + 64 * LS;
  __bf16* wl = wh + 64 * LS;
  float*  cl = (float*)smem;

  const int t = threadIdx.x;
  const int l = t & 63;
  const int wc = (t >> 6) * 16;
  const int rowbase = blockIdx.x * 64;

  f32x4 acc[4];
  #pragma unroll
  for (int rt = 0; rt < 4; ++rt) acc[rt] = (f32x4){0.f, 0.f, 0.f, 0.f};

  const int sr = t >> 2;
  const int kc = (t & 3) * 8;

  for (int kt = 0; kt < NT; ++kt) {
    __syncthreads();
    {
      int gr = rowbase + sr;
      float4 v0 = make_float4(0.f, 0.f, 0.f, 0.f), v1 = v0;
      if (gr < NN) {
        const float* xp = X + (size_t)gr * K + kt * KT + kc;
        v0 = *reinterpret_cast<const float4*>(xp);
        v1 = *reinterpret_cast<const float4*>(xp + 4);
      }
      float e[8] = {v0.x, v0.y, v0.z, v0.w, v1.x, v1.y, v1.z, v1.w};
      bf16v8 hv, lv;
      #pragma unroll
      for (int j = 0; j < 8; ++j) {
        __bf16 h = (__bf16)e[j];
        hv[j] = h;
        lv[j] = (__bf16)(e[j] - (float)h);
      }
      *reinterpret_cast<bf16v8*>(&xh[sr * LS + kc]) = hv;
      *reinterpret_cast<bf16v8*>(&xl[sr * LS + kc]) = lv;
      *reinterpret_cast<bf16v8*>(&wh[sr * LS + kc]) =
          *reinterpret_cast<const bf16v8*>(Whi + (size_t)sr * K + kt * KT + kc);
      *reinterpret_cast<bf16v8*>(&wl[sr * LS + kc]) =
          *reinterpret_cast<const bf16v8*>(Wlo + (size_t)sr * K + kt * KT + kc);
    }
    __syncthreads();

    const int bo = (wc + (l & 15)) * LS + (l >> 4) * 8;
    bf16v8 bh = *reinterpret_cast<const bf16v8*>(&wh[bo]);
    bf16v8 bl = *reinterpret_cast<const bf16v8*>(&wl[bo]);
    #pragma unroll
    for (int rt = 0; rt < 4; ++rt) {
      const int ao = (rt * 16 + (l & 15)) * LS + (l >> 4) * 8;
      bf16v8 ah = *reinterpret_cast<const bf16v8*>(&xh[ao]);
      bf16v8 al = *reinterpret_cast<const bf16v8*>(&xl[ao]);
      acc[rt] = __builtin_amdgcn_mfma_f32_16x16x32_bf16(ah, bh, acc[rt], 0, 0, 0);
      acc[rt] = __builtin_amdgcn_mfma_f32_16x16x32_bf16(al, bh, acc[rt], 0, 0, 0);
      acc[rt] = __builtin_amdgcn_mfma_f32_16x16x32_bf16(ah, bl, acc[rt], 0, 0, 0);
    }
  }

  __syncthreads();
  #pragma unroll
  for (int rt = 0; rt < 4; ++rt)
    #pragma unroll
    for (int j = 0; j < 4; ++j)
      cl[(rt * 16 + (l >> 4) * 4 + j) * CS + wc + (l & 15)] = acc[rt][j];
  __syncthreads();

  const int r = t >> 2, cc = (t & 3) * 16;
  const int grow = rowbase + r;
  if (grow < NN) {
    if (MODE == 0) {
      float dv = dinv[grow];
      bf16v8 o0, o1;
      #pragma unroll
      for (int j = 0; j < 8; ++j) o0[j] = (__bf16)(cl[r * CS + cc + j] * dv);
      #pragma unroll
      for (int j = 0; j < 8; ++j) o1[j] = (__bf16)(cl[r * CS + cc + 8 + j] * dv);
      __bf16* yp = (__bf16*)Yv + (size_t)grow * HID + cc;
      *reinterpret_cast<bf16v8*>(yp) = o0;
      *reinterpret_cast<bf16v8*>(yp + 8) = o1;
    } else {
      float* yp = (float*)Yv + (size_t)grow * HID + cc;
      #pragma unroll
      for (int c4 = 0; c4 < 4; ++c4) {
        float4 o;
        o.x = fmaxf(cl[r * CS + cc + c4 * 4 + 0] + bias[cc + c4 * 4 + 0], 0.f);
        o.y = fmaxf(cl[r * CS + cc + c4 * 4 + 1] + bias[cc + c4 * 4 + 1], 0.f);
        o.z = fmaxf(cl[r * CS + cc + c4 * 4 + 2] + bias[cc + c4 * 4 + 2], 0.f);
        o.w = fmaxf(cl[r * CS + cc + c4 * 4 + 3] + bias[cc + c4 * 4 + 3], 0.f);
        *reinterpret_cast<float4*>(yp + c4 * 4) = o;
      }
    }
  }
}

// ---------- fused bucket-local aggregation: block = bucket (128 nodes), LDS fp32 accumulator.
// Waves stream bucket edges (16 gathers in flight); lane = feature; LDS atomic fadd is
// lane-striped (2 lanes/bank = free). Self-loop + epilogue at writeout.
// MODE 0 (layer1): O(bf16) = dinv*relu(dinv*sum + bias); MODE 1 (layer2): O(fp32) = dinv*sum.
template<int MODE>
__global__ void __launch_bounds__(1024)
k_aggf(const unsigned short* __restrict__ T, const unsigned* __restrict__ binned,
       const int* __restrict__ basep, const int* __restrict__ tot,
       const float* __restrict__ dinv, const float* __restrict__ bias, void* __restrict__ Ov) {
  __shared__ float facc[NPB * 64];   // 32 KB
  const int t = threadIdx.x;
  const int b = blockIdx.x;
  #pragma unroll
  for (int i = t; i < NPB * 64; i += 1024) facc[i] = 0.f;
  __syncthreads();

  const int lane = t & 63;
  const int w = t >> 6;              // 16 waves
  const int s = basep[b], n = tot[b];

  for (int base0 = w * 64; base0 < n; base0 += 16 * 64) {
    int m = min(64, n - base0);
    unsigned epk = (lane < m) ? binned[s + base0 + lane] : 0u;   // coalesced
    for (int c0 = 0; c0 < m; c0 += 16) {
      #pragma unroll
      for (int i = 0; i < 16; ++i) {
        int j = c0 + i;
        unsigned ee = __shfl(epk, j & 63);
        int src = (int)(ee & 0x1FFFFu);
        int dl  = (int)(ee >> 17);
        float v = bf2f(T[(size_t)src * 64 + lane]);   // 128B row gather, 16 in flight
        if (j < m) unsafeAtomicAdd(&facc[dl * 64 + lane], v);
      }
    }
  }
  __syncthreads();

  for (int sIdx = t; sIdx < NPB * 64; sIdx += 1024) {
    int nn = sIdx >> 6, f = sIdx & 63;
    int g = b * NPB + nn;
    if (g < NN) {
      float self = bf2f(T[(size_t)g * 64 + f]);
      float sum = facc[sIdx] + self;
      float dv = dinv[g];
      if (MODE == 0) {
        ((unsigned short*)Ov)[(size_t)g * 64 + f] = f2bf(dv * fmaxf(fmaf(dv, sum, bias[f]), 0.f));
      } else {
        ((float*)Ov)[(size_t)g * 64 + f] = dv * sum;
      }
    }
  }
}

extern "C" void kernel_launch(void* const* d_in, const int* in_sizes, int n_in,
                              void* d_out, int out_size, void* d_ws, size_t ws_size,
                              hipStream_t stream) {
  const float* x  = (const float*)d_in[0];
  const int*   ed = (const int*)d_in[1];   // int32 per harness contract
  const float* W1 = (const float*)d_in[2];
  const float* b1 = (const float*)d_in[3];
  const float* W2 = (const float*)d_in[4];
  const float* b2 = (const float*)d_in[5];
  float* out = (float*)d_out;

  char* ws = (char*)d_ws;
  size_t off = 0;
  auto alloc = [&](size_t bytes) {
    char* p = ws + off;
    off = (off + bytes + 255) & ~(size_t)255;
    return p;
  };
  int*      deg    = (int*)alloc((size_t)NN * 4);
  float*    dinv   = (float*)alloc((size_t)NN * 4);
  unsigned* binned = (unsigned*)alloc((size_t)NE * 4);
  int*      bcnt   = (int*)alloc((size_t)NBK * NB * 4);
  int*      tot    = (int*)alloc((size_t)NB * 4);
  int*      basep  = (int*)alloc((size_t)NB * 4);
  // A: first bf16 t1' table (12.8 MB), later fp32 g (25.6 MB)
  float*    A      = (float*)alloc((size_t)NN * HID * 4);
  __bf16*   Whi1   = (__bf16*)alloc((size_t)HID * KIN * 2);
  __bf16*   Wlo1   = (__bf16*)alloc((size_t)HID * KIN * 2);
  __bf16*   Whi2   = (__bf16*)alloc((size_t)HID * HID * 2);
  __bf16*   Wlo2   = (__bf16*)alloc((size_t)HID * HID * 2);
  // h' (bf16, 12.8 MB) lives in d_out's first half; final GEMM overwrites all of d_out.
  unsigned short* Hp = (unsigned short*)d_out;

  // ---- bucket binning (counting sort to 128-node granularity)
  k_bhist<<<NBK, 256, 0, stream>>>(ed, bcnt);
  k_bscan1<<<(NB + 255) / 256, 256, 0, stream>>>(bcnt, tot);
  k_bscan2<<<1, 1024, 0, stream>>>(tot, basep);
  k_bin<<<NBK, 256, 0, stream>>>(ed, bcnt, basep, binned);
  k_degb<<<NB, 256, 0, stream>>>(binned, basep, tot, deg);
  k_dinv<<<(NN + 255) / 256, 256, 0, stream>>>(deg, dinv);
  k_wconv<<<(HID * KIN + 255) / 256, 256, 0, stream>>>(W1, Whi1, Wlo1, HID * KIN);
  k_wconv<<<(HID * HID + 255) / 256, 256, 0, stream>>>(W2, Whi2, Wlo2, HID * HID);

  const int GB = (NN + 63) / 64;  // 1563 gemm blocks

  // layer 1: A(bf16) = dinv .* (x @ W1^T) ; Hp(bf16) = dinv .* relu(dinv.*(Agg A) + b1)
  k_gemm<KIN, 0><<<GB, 256, 0, stream>>>(x, Whi1, Wlo1, dinv, b1, A);
  k_aggf<0><<<NB, 1024, 0, stream>>>((const unsigned short*)A, binned, basep, tot, dinv, b1, Hp);

  // layer 2 (agg commutes with right-linear): A(fp32 g) = dinv .* (Agg Hp) ;
  //          out = relu(g @ W2^T + b2)
  k_aggf<1><<<NB, 1024, 0, stream>>>(Hp, binned, basep, tot, dinv, b2, A);
  k_gemm<HID, 1><<<GB, 256, 0, stream>>>((const float*)A, Whi2, Wlo2, dinv, b2, out);
}

// Round 14
// 182.219 us; speedup vs baseline: 6.2470x; 6.2470x over previous
//
#include <hip/hip_runtime.h>

static constexpr int NN  = 100000;   // nodes
static constexpr int NE  = 1200000;  // edges
static constexpr int KIN = 256;      // input dim
static constexpr int HID = 64;       // hidden == output dim

static constexpr int BSH   = 7;                        // log2 nodes-per-bucket
static constexpr int NPB   = 1 << BSH;                 // 128 nodes per bucket
static constexpr int NB    = (NN + NPB - 1) / NPB;     // 782 buckets
static constexpr int CHUNK = 8192;                     // edges per binning block
static constexpr int NBK   = (NE + CHUNK - 1) / CHUNK; // 147 binning blocks

typedef __attribute__((ext_vector_type(8))) __bf16 bf16v8;
typedef __attribute__((ext_vector_type(4))) float f32x4;

// ---------- bf16 helpers (exact widen; RNE narrow)
__device__ __forceinline__ float bf2f(unsigned short u) {
  return __uint_as_float(((unsigned int)u) << 16);
}
__device__ __forceinline__ unsigned short f2bf(float f) {
  unsigned int b = __float_as_uint(f);
  return (unsigned short)((b + 0x7FFFu + ((b >> 16) & 1u)) >> 16);
}

// ---------- W fp32 -> bf16 hi/lo tables (hi = RNE(bf16), lo = RNE(x - hi))
__global__ void k_wconv(const float* __restrict__ Wsrc, __bf16* __restrict__ Whi,
                        __bf16* __restrict__ Wlo, int n) {
  int i = blockIdx.x * 256 + threadIdx.x;
  if (i < n) {
    float v = Wsrc[i];
    __bf16 h = (__bf16)v;
    Whi[i] = h;
    Wlo[i] = (__bf16)(v - (float)h);
  }
}

// ---------- pass 1: per-(block,bucket) histogram of dst buckets
__global__ void __launch_bounds__(256) k_bhist(const int* __restrict__ ed, int* __restrict__ bcnt) {
  __shared__ int lcnt[NB];
  int t = threadIdx.x, blk = blockIdx.x;
  for (int i = t; i < NB; i += 256) lcnt[i] = 0;
  __syncthreads();
  int base = blk * CHUNK;
  #pragma unroll
  for (int it = 0; it < CHUNK / 256; ++it) {
    int e = base + it * 256 + t;
    if (e < NE) atomicAdd(&lcnt[ed[NE + e] >> BSH], 1);
  }
  __syncthreads();
  for (int i = t; i < NB; i += 256) bcnt[blk * NB + i] = lcnt[i];
}

// ---------- scan A: per bucket, exclusive prefix over blocks (in place) + totals
__global__ void k_bscan1(int* __restrict__ bcnt, int* __restrict__ tot) {
  int b = blockIdx.x * 256 + threadIdx.x;
  if (b >= NB) return;
  int run = 0;
  for (int k = 0; k < NBK; ++k) {
    int v = bcnt[k * NB + b];
    bcnt[k * NB + b] = run;
    run += v;
  }
  tot[b] = run;
}

// ---------- scan B: exclusive prefix over bucket totals
__global__ void k_bscan2(const int* __restrict__ tot, int* __restrict__ basep) {
  __shared__ int sh[1024];
  int t = threadIdx.x;
  int v = (t < NB) ? tot[t] : 0;
  sh[t] = v;
  __syncthreads();
  #pragma unroll
  for (int off = 1; off < 1024; off <<= 1) {
    int x = (t >= off) ? sh[t - off] : 0;
    __syncthreads();
    sh[t] += x;
    __syncthreads();
  }
  if (t < NB) basep[t] = sh[t] - v;  // exclusive
}

// ---------- pass 2: scatter edges into bucket-grouped array (contiguous per block/bucket)
__global__ void __launch_bounds__(256) k_bin(const int* __restrict__ ed, const int* __restrict__ bcnt,
                                             const int* __restrict__ basep, unsigned* __restrict__ binned) {
  __shared__ int lcnt[NB];
  int t = threadIdx.x, blk = blockIdx.x;
  for (int i = t; i < NB; i += 256) lcnt[i] = 0;
  __syncthreads();
  int base = blk * CHUNK;
  #pragma unroll
  for (int it = 0; it < CHUNK / 256; ++it) {
    int e = base + it * 256 + t;
    if (e < NE) {
      int src = ed[e];
      int dst = ed[NE + e];
      int b = dst >> BSH;
      int r = atomicAdd(&lcnt[b], 1);
      int pos = basep[b] + bcnt[blk * NB + b] + r;
      binned[pos] = (unsigned)src | ((unsigned)(dst & (NPB - 1)) << 17);
    }
  }
}

// ---------- per-bucket degree count (LDS-local, no global random atomics)
__global__ void __launch_bounds__(256) k_degb(const unsigned* __restrict__ binned,
                                              const int* __restrict__ basep, const int* __restrict__ tot,
                                              int* __restrict__ deg) {
  __shared__ int d[NPB];
  int t = threadIdx.x, b = blockIdx.x;
  if (t < NPB) d[t] = 0;
  __syncthreads();
  int s = basep[b], n = tot[b];
  for (int i = t; i < n; i += 256) atomicAdd(&d[binned[s + i] >> 17], 1);
  __syncthreads();
  int node = b * NPB + t;
  if (t < NPB && node < NN) deg[node] = d[t];
}

__global__ void k_dinv(const int* __restrict__ deg, float* __restrict__ dinv) {
  int i = blockIdx.x * 256 + threadIdx.x;
  if (i < NN) dinv[i] = rsqrtf((float)(deg[i] + 1));
}

// ---------- exclusive scan of deg -> row_ptr (1024 elems/block -> nb = 98 blocks)
__global__ void k_scan1(const int* __restrict__ deg, int* __restrict__ rp, int* __restrict__ bsum) {
  __shared__ int sh[256];
  int t = threadIdx.x;
  int base = blockIdx.x * 1024 + t * 4;
  int v0 = 0, v1 = 0, v2 = 0, v3 = 0;
  if (base + 0 < NN) v0 = deg[base + 0];
  if (base + 1 < NN) v1 = deg[base + 1];
  if (base + 2 < NN) v2 = deg[base + 2];
  if (base + 3 < NN) v3 = deg[base + 3];
  int s = v0 + v1 + v2 + v3;
  sh[t] = s;
  __syncthreads();
  #pragma unroll
  for (int off = 1; off < 256; off <<= 1) {
    int x = (t >= off) ? sh[t - off] : 0;
    __syncthreads();
    sh[t] += x;
    __syncthreads();
  }
  int pre = sh[t] - s;
  if (t == 255) bsum[blockIdx.x] = sh[255];
  if (base + 0 < NN) rp[base + 0] = pre;
  pre += v0;
  if (base + 1 < NN) rp[base + 1] = pre;
  pre += v1;
  if (base + 2 < NN) rp[base + 2] = pre;
  pre += v2;
  if (base + 3 < NN) rp[base + 3] = pre;
}

__global__ void k_scan2(int* __restrict__ bsum, int nb) {
  __shared__ int sh[128];
  int t = threadIdx.x;
  int v = (t < nb) ? bsum[t] : 0;
  sh[t] = v;
  __syncthreads();
  #pragma unroll
  for (int off = 1; off < 128; off <<= 1) {
    int x = (t >= off) ? sh[t - off] : 0;
    __syncthreads();
    sh[t] += x;
    __syncthreads();
  }
  if (t < nb) bsum[t] = sh[t] - v;  // exclusive
}

__global__ void k_scan3(int* __restrict__ rp, const int* __restrict__ bsum) {
  int i = blockIdx.x * 256 + threadIdx.x;
  if (i < NN) rp[i] += bsum[i >> 10];
}

// ---------- bucket-local CSR build: one block per bucket; ranks via LDS atomics;
// csr writes confined to the bucket's contiguous edge window (L2-friendly).
__global__ void __launch_bounds__(256) k_csr(const unsigned* __restrict__ binned,
                                             const int* __restrict__ basep, const int* __restrict__ tot,
                                             const int* __restrict__ rp, int* __restrict__ csr) {
  __shared__ int srp[NPB];
  __shared__ int cur[NPB];
  int t = threadIdx.x, b = blockIdx.x;
  if (t < NPB) {
    int node = b * NPB + t;
    srp[t] = (node < NN) ? rp[node] : 0;
    cur[t] = 0;
  }
  __syncthreads();
  int s = basep[b], n = tot[b];
  for (int i = t; i < n; i += 256) {
    unsigned u = binned[s + i];
    int src = (int)(u & 0x1FFFFu);
    int dl  = (int)(u >> 17);
    int r = atomicAdd(&cur[dl], 1);
    csr[srp[dl] + r] = src;
  }
}

// ---------- MFMA GEMM: Y = X @ W^T via bf16 hi/lo 3-term split (~fp32 accurate)
template<int K, int MODE>
__global__ void __launch_bounds__(256, 4)
k_gemm(const float* __restrict__ X, const __bf16* __restrict__ Whi, const __bf16* __restrict__ Wlo,
       const float* __restrict__ dinv, const float* __restrict__ bias, void* __restrict__ Yv) {
  constexpr int KT = 32;
  constexpr int NT = K / KT;
  constexpr int LS = 40;
  constexpr int CS = 68;
  __shared__ __align__(16) char smem[4 * 64 * LS * 2];
  __bf16* xh = (__bf16*)smem;
  __bf16* xl = xh + 64 * LS;
  __bf16* wh = xl + 64 * LS;
  __bf16* wl = wh + 64 * LS;
  float*  cl = (float*)smem;

  const int t = threadIdx.x;
  const int l = t & 63;
  const int wc = (t >> 6) * 16;
  const int rowbase = blockIdx.x * 64;

  f32x4 acc[4];
  #pragma unroll
  for (int rt = 0; rt < 4; ++rt) acc[rt] = (f32x4){0.f, 0.f, 0.f, 0.f};

  const int sr = t >> 2;
  const int kc = (t & 3) * 8;

  for (int kt = 0; kt < NT; ++kt) {
    __syncthreads();
    {
      int gr = rowbase + sr;
      float4 v0 = make_float4(0.f, 0.f, 0.f, 0.f), v1 = v0;
      if (gr < NN) {
        const float* xp = X + (size_t)gr * K + kt * KT + kc;
        v0 = *reinterpret_cast<const float4*>(xp);
        v1 = *reinterpret_cast<const float4*>(xp + 4);
      }
      float e[8] = {v0.x, v0.y, v0.z, v0.w, v1.x, v1.y, v1.z, v1.w};
      bf16v8 hv, lv;
      #pragma unroll
      for (int j = 0; j < 8; ++j) {
        __bf16 h = (__bf16)e[j];
        hv[j] = h;
        lv[j] = (__bf16)(e[j] - (float)h);
      }
      *reinterpret_cast<bf16v8*>(&xh[sr * LS + kc]) = hv;
      *reinterpret_cast<bf16v8*>(&xl[sr * LS + kc]) = lv;
      *reinterpret_cast<bf16v8*>(&wh[sr * LS + kc]) =
          *reinterpret_cast<const bf16v8*>(Whi + (size_t)sr * K + kt * KT + kc);
      *reinterpret_cast<bf16v8*>(&wl[sr * LS + kc]) =
          *reinterpret_cast<const bf16v8*>(Wlo + (size_t)sr * K + kt * KT + kc);
    }
    __syncthreads();

    const int bo = (wc + (l & 15)) * LS + (l >> 4) * 8;
    bf16v8 bh = *reinterpret_cast<const bf16v8*>(&wh[bo]);
    bf16v8 bl = *reinterpret_cast<const bf16v8*>(&wl[bo]);
    #pragma unroll
    for (int rt = 0; rt < 4; ++rt) {
      const int ao = (rt * 16 + (l & 15)) * LS + (l >> 4) * 8;
      bf16v8 ah = *reinterpret_cast<const bf16v8*>(&xh[ao]);
      bf16v8 al = *reinterpret_cast<const bf16v8*>(&xl[ao]);
      acc[rt] = __builtin_amdgcn_mfma_f32_16x16x32_bf16(ah, bh, acc[rt], 0, 0, 0);
      acc[rt] = __builtin_amdgcn_mfma_f32_16x16x32_bf16(al, bh, acc[rt], 0, 0, 0);
      acc[rt] = __builtin_amdgcn_mfma_f32_16x16x32_bf16(ah, bl, acc[rt], 0, 0, 0);
    }
  }

  __syncthreads();
  #pragma unroll
  for (int rt = 0; rt < 4; ++rt)
    #pragma unroll
    for (int j = 0; j < 4; ++j)
      cl[(rt * 16 + (l >> 4) * 4 + j) * CS + wc + (l & 15)] = acc[rt][j];
  __syncthreads();

  const int r = t >> 2, cc = (t & 3) * 16;
  const int grow = rowbase + r;
  if (grow < NN) {
    if (MODE == 0) {
      float dv = dinv[grow];
      bf16v8 o0, o1;
      #pragma unroll
      for (int j = 0; j < 8; ++j) o0[j] = (__bf16)(cl[r * CS + cc + j] * dv);
      #pragma unroll
      for (int j = 0; j < 8; ++j) o1[j] = (__bf16)(cl[r * CS + cc + 8 + j] * dv);
      __bf16* yp = (__bf16*)Yv + (size_t)grow * HID + cc;
      *reinterpret_cast<bf16v8*>(yp) = o0;
      *reinterpret_cast<bf16v8*>(yp + 8) = o1;
    } else {
      float* yp = (float*)Yv + (size_t)grow * HID + cc;
      #pragma unroll
      for (int c4 = 0; c4 < 4; ++c4) {
        float4 o;
        o.x = fmaxf(cl[r * CS + cc + c4 * 4 + 0] + bias[cc + c4 * 4 + 0], 0.f);
        o.y = fmaxf(cl[r * CS + cc + c4 * 4 + 1] + bias[cc + c4 * 4 + 1], 0.f);
        o.z = fmaxf(cl[r * CS + cc + c4 * 4 + 2] + bias[cc + c4 * 4 + 2], 0.f);
        o.w = fmaxf(cl[r * CS + cc + c4 * 4 + 3] + bias[cc + c4 * 4 + 3], 0.f);
        *reinterpret_cast<float4*>(yp + c4 * 4) = o;
      }
    }
  }
}

// ---------- aggregation over pre-scaled bf16 rows T' (= dinv.*T). One wave per node,
// lane = feature. Fixed 16-wide predicated gather (16 loads in flight). fp32 accumulate.
// MODE 0 (layer1): O(bf16) = dinv[node] * relu(dinv[node]*sum + bias[lane])   (h')
// MODE 1 (layer2): O(fp32) = dinv[node] * sum                                 (g)
template<int MODE>
__global__ void __launch_bounds__(256, 8)
k_agg(const unsigned short* __restrict__ T, const int* __restrict__ csr,
      const int* __restrict__ rp, const int* __restrict__ deg,
      const float* __restrict__ dinv, const float* __restrict__ bias,
      void* __restrict__ Ov) {
  int node = blockIdx.x * 4 + (threadIdx.x >> 6);
  int lane = threadIdx.x & 63;
  float acc = bf2f(T[(size_t)node * HID + lane]);   // self-loop term (pre-scaled)
  int start = rp[node];
  int len = deg[node];
  for (int base = 0; base < len; base += 64) {
    int m = min(64, len - base);
    int idx = (lane < m) ? csr[start + base + lane] : 0;   // coalesced index load
    for (int c0 = 0; c0 < m; c0 += 16) {
      float part = 0.f;
      #pragma unroll
      for (int i = 0; i < 16; ++i) {
        int e = c0 + i;
        int s = __shfl(idx, e & 63);
        float v = bf2f(T[(size_t)s * HID + lane]);   // always issued; 16 in flight
        part += (e < m) ? v : 0.f;
      }
      acc += part;
    }
  }
  float dv = dinv[node];
  if (MODE == 0) {
    float h = dv * fmaxf(fmaf(dv, acc, bias[lane]), 0.f);
    ((unsigned short*)Ov)[(size_t)node * HID + lane] = f2bf(h);
  } else {
    ((float*)Ov)[(size_t)node * HID + lane] = dv * acc;
  }
}

extern "C" void kernel_launch(void* const* d_in, const int* in_sizes, int n_in,
                              void* d_out, int out_size, void* d_ws, size_t ws_size,
                              hipStream_t stream) {
  const float* x  = (const float*)d_in[0];
  const int*   ed = (const int*)d_in[1];   // int32 per harness contract
  const float* W1 = (const float*)d_in[2];
  const float* b1 = (const float*)d_in[3];
  const float* W2 = (const float*)d_in[4];
  const float* b2 = (const float*)d_in[5];
  float* out = (float*)d_out;

  char* ws = (char*)d_ws;
  size_t off = 0;
  auto alloc = [&](size_t bytes) {
    char* p = ws + off;
    off = (off + bytes + 255) & ~(size_t)255;
    return p;
  };
  int*      deg    = (int*)alloc((size_t)NN * 4);
  float*    dinv   = (float*)alloc((size_t)NN * 4);
  int*      rp     = (int*)alloc((size_t)NN * 4);
  int*      bsum   = (int*)alloc(4096);
  unsigned* binned = (unsigned*)alloc((size_t)NE * 4);
  int*      csr    = (int*)alloc((size_t)NE * 4);
  int*      bcnt   = (int*)alloc((size_t)NBK * NB * 4);
  int*      tot    = (int*)alloc((size_t)NB * 4);
  int*      basep  = (int*)alloc((size_t)NB * 4);
  // A: first bf16 t1' table (12.8 MB), later fp32 g (25.6 MB)
  float*    A      = (float*)alloc((size_t)NN * HID * 4);
  __bf16*   Whi1   = (__bf16*)alloc((size_t)HID * KIN * 2);
  __bf16*   Wlo1   = (__bf16*)alloc((size_t)HID * KIN * 2);
  __bf16*   Whi2   = (__bf16*)alloc((size_t)HID * HID * 2);
  __bf16*   Wlo2   = (__bf16*)alloc((size_t)HID * HID * 2);
  // h' (bf16, 12.8 MB) lives in d_out's first half; final GEMM overwrites all of d_out.
  unsigned short* Hp = (unsigned short*)d_out;

  // ---- bucket binning -> per-node CSR (all writes bucket-contiguous)
  k_bhist<<<NBK, 256, 0, stream>>>(ed, bcnt);
  k_bscan1<<<(NB + 255) / 256, 256, 0, stream>>>(bcnt, tot);
  k_bscan2<<<1, 1024, 0, stream>>>(tot, basep);
  k_bin<<<NBK, 256, 0, stream>>>(ed, bcnt, basep, binned);
  k_degb<<<NB, 256, 0, stream>>>(binned, basep, tot, deg);
  k_dinv<<<(NN + 255) / 256, 256, 0, stream>>>(deg, dinv);
  int nb = (NN + 1023) / 1024;   // 98
  k_scan1<<<nb, 256, 0, stream>>>(deg, rp, bsum);
  k_scan2<<<1, 128, 0, stream>>>(bsum, nb);
  k_scan3<<<(NN + 255) / 256, 256, 0, stream>>>(rp, bsum);
  k_csr<<<NB, 256, 0, stream>>>(binned, basep, tot, rp, csr);
  k_wconv<<<(HID * KIN + 255) / 256, 256, 0, stream>>>(W1, Whi1, Wlo1, HID * KIN);
  k_wconv<<<(HID * HID + 255) / 256, 256, 0, stream>>>(W2, Whi2, Wlo2, HID * HID);

  const int GB = (NN + 63) / 64;  // 1563 gemm blocks

  // layer 1: A(bf16) = dinv .* (x @ W1^T) ; Hp(bf16) = dinv .* relu(dinv.*(Agg A) + b1)
  k_gemm<KIN, 0><<<GB, 256, 0, stream>>>(x, Whi1, Wlo1, dinv, b1, A);
  k_agg<0><<<NN / 4, 256, 0, stream>>>((const unsigned short*)A, csr, rp, deg, dinv, b1, Hp);

  // layer 2 (agg commutes with right-linear): A(fp32 g) = dinv .* (Agg Hp) ;
  //          out = relu(g @ W2^T + b2)
  k_agg<1><<<NN / 4, 256, 0, stream>>>(Hp, csr, rp, deg, dinv, b2, A);
  k_gemm<HID, 1><<<GB, 256, 0, stream>>>((const float*)A, Whi2, Wlo2, dinv, b2, out);
}